// Round 5
// baseline (441.047 us; speedup 1.0000x reference)
//
#include <hip/hip_runtime.h>
#include <stdint.h>

// Problem constants
#define B_    64
#define T_    4096
#define D_    256
#define A_    50
#define APAD  64
#define TB    256            // T-rows per block
#define ST    32             // T-rows per subtile
#define NSUB  (TB / ST)      // 8
#define WT_STRIDE 264
#define XS_STRIDE 264
#define EPS_  1e-7f

// ws float layout:
#define OFF_B   0
#define OFF_U   64
#define OFF_WT  128                    // Wt bf16 [64][264] = 8448 floats
#define OFF_NP  (OFF_WT + 8448)        // num partials [64][16][256]
#define OFF_DP  (OFF_NP + 64*16*256)   // den partials [64][16]

typedef __attribute__((ext_vector_type(8))) short short8;
typedef __attribute__((ext_vector_type(4))) float floatx4;

__device__ __forceinline__ unsigned short f32_to_bf16(float f) {
    union { float f; uint32_t u; } v; v.f = f;
    uint32_t u = v.u;
    uint32_t r = u + 0x7FFFu + ((u >> 16) & 1u);   // RNE
    return (unsigned short)(r >> 16);
}

__device__ __forceinline__ float fast_tanh(float x) {
    float e2 = __expf(2.0f * x);
    return (e2 - 1.0f) * __builtin_amdgcn_rcpf(e2 + 1.0f);
}

// ---------------- prologue: pack W/b/u ----------------
__global__ void att_prologue(const float* __restrict__ W,
                             const float* __restrict__ bias,
                             const float* __restrict__ u,
                             float* __restrict__ ws) {
    int idx = blockIdx.x * blockDim.x + threadIdx.x;
    int stride = gridDim.x * blockDim.x;
    for (int i = idx; i < APAD; i += stride) {
        ws[OFF_B + i] = (i < A_) ? bias[i] : 0.0f;
        ws[OFF_U + i] = (i < A_) ? u[i]    : 0.0f;
    }
    unsigned short* wt = (unsigned short*)(ws + OFF_WT);
    for (int i = idx; i < APAD * D_; i += stride) {
        int a = i >> 8;          // 0..63
        int k = i & 255;         // 0..255
        float val = (a < A_) ? W[k * A_ + a] : 0.0f;
        wt[a * WT_STRIDE + k] = f32_to_bf16(val);
    }
}

// ---------------- main fused kernel ----------------
// wave w owns n-tile w; W B-fragments in registers; phase-2 from fp32 registers.
__global__ __launch_bounds__(256, 3) void att_main(const float* __restrict__ x,
                                                   float* __restrict__ ws) {
    __shared__ unsigned short lds_x[ST * XS_STRIDE];  // 16896 B (reused as reduction buf)
    __shared__ float part[ST][4];
    __shared__ float e_lds[ST];

    const int tid  = threadIdx.x;
    const int wave = tid >> 6;
    const int lane = tid & 63;
    const int bb   = blockIdx.y;
    const int tblk = blockIdx.x;

    const float* xblk = x + ((size_t)bb * T_ + (size_t)tblk * TB) * D_;

    // ping-pong register tiles; thread owns rows {tid>>5 + 8i}, cols 8(tid&31)..+7
    floatx4 rA[8], rB[8];
    {
        const floatx4* xg = (const floatx4*)xblk;
        #pragma unroll
        for (int i = 0; i < 4; ++i) {
            rA[2*i]   = __builtin_nontemporal_load(&xg[2*tid + 512*i]);
            rA[2*i+1] = __builtin_nontemporal_load(&xg[2*tid + 512*i + 1]);
        }
    }

    // this wave's B-fragments (n-tile = wave), loaded once
    short8 bw[8];
    {
        const unsigned short* wt = (const unsigned short*)(ws + OFF_WT);
        const unsigned short* wrow = wt + (wave * 16 + (lane & 15)) * WT_STRIDE
                                        + ((lane >> 4) * 8);
        #pragma unroll
        for (int ks = 0; ks < 8; ++ks)
            bw[ks] = *(const short8*)(wrow + ks * 32);
    }

    const int c = wave * 16 + (lane & 15);
    const float b_c = ws[OFF_B + c];
    const float u_c = ws[OFF_U + c];

    float num_part[8] = {0.f,0.f,0.f,0.f,0.f,0.f,0.f,0.f};
    float den_acc = 0.0f;   // tid < ST only

    const int arow0 = (lane & 15) * XS_STRIDE;
    const int arow1 = (16 + (lane & 15)) * XS_STRIDE;
    const int koff  = (lane >> 4) * 8;
    const int wrow_lds = (tid >> 5) * XS_STRIDE + (tid & 31) * 8;
    const int erow = tid >> 5;

    auto body = [&](int st, floatx4 (&rc)[8], floatx4 (&rn)[8]) {
        __syncthreads();  // S0: lds_x free

        // phase 1: rc -> bf16 LDS tile (one ds_write_b128 per i)
        #pragma unroll
        for (int i = 0; i < 4; ++i) {
            uint4 p;
            p.x = ((uint32_t)f32_to_bf16(rc[2*i][1])   << 16) | f32_to_bf16(rc[2*i][0]);
            p.y = ((uint32_t)f32_to_bf16(rc[2*i][3])   << 16) | f32_to_bf16(rc[2*i][2]);
            p.z = ((uint32_t)f32_to_bf16(rc[2*i+1][1]) << 16) | f32_to_bf16(rc[2*i+1][0]);
            p.w = ((uint32_t)f32_to_bf16(rc[2*i+1][3]) << 16) | f32_to_bf16(rc[2*i+1][2]);
            *(uint4*)&lds_x[wrow_lds + i * 8 * XS_STRIDE] = p;
        }
        __syncthreads();  // S1: tile ready

        // early-issue next subtile's loads into rn (in flight across compute)
        if (st + 1 < NSUB) {
            const floatx4* xn = (const floatx4*)(xblk + (st + 1) * ST * D_);
            #pragma unroll
            for (int i = 0; i < 4; ++i) {
                rn[2*i]   = __builtin_nontemporal_load(&xn[2*tid + 512*i]);
                rn[2*i+1] = __builtin_nontemporal_load(&xn[2*tid + 512*i + 1]);
            }
        }

        // MFMA: preact[32 x 16] for this wave's n-tile
        floatx4 acc0 = {0.f, 0.f, 0.f, 0.f};
        floatx4 acc1 = {0.f, 0.f, 0.f, 0.f};
        #pragma unroll
        for (int ks = 0; ks < 8; ++ks) {
            short8 a0 = *(const short8*)&lds_x[arow0 + ks * 32 + koff];
            short8 a1 = *(const short8*)&lds_x[arow1 + ks * 32 + koff];
            acc0 = __builtin_amdgcn_mfma_f32_16x16x32_bf16(a0, bw[ks], acc0, 0, 0, 0);
            acc1 = __builtin_amdgcn_mfma_f32_16x16x32_bf16(a1, bw[ks], acc1, 0, 0, 0);
        }

        // logit partials: tanh(preact+b)*u, reduce over 16 cols
        float lp0[4], lp1[4];
        #pragma unroll
        for (int rr = 0; rr < 4; ++rr) {
            float v0 = fast_tanh(acc0[rr] + b_c) * u_c;
            float v1 = fast_tanh(acc1[rr] + b_c) * u_c;
            v0 += __shfl_xor(v0, 1); v1 += __shfl_xor(v1, 1);
            v0 += __shfl_xor(v0, 2); v1 += __shfl_xor(v1, 2);
            v0 += __shfl_xor(v0, 4); v1 += __shfl_xor(v1, 4);
            v0 += __shfl_xor(v0, 8); v1 += __shfl_xor(v1, 8);
            lp0[rr] = v0; lp1[rr] = v1;
        }
        if ((lane & 15) == 0) {
            int rg = lane >> 4;
            #pragma unroll
            for (int rr = 0; rr < 4; ++rr) {
                part[rg * 4 + rr][wave]      = lp0[rr];
                part[16 + rg * 4 + rr][wave] = lp1[rr];
            }
        }
        __syncthreads();  // S2

        if (tid < ST) {
            float ev = __expf(part[tid][0] + part[tid][1] + part[tid][2] + part[tid][3]);
            e_lds[tid] = ev;
            den_acc += ev;
        }
        __syncthreads();  // S3: e ready

        // phase 2 (register, fp32): num_part[j] += e[row_i] * x_reg
        #pragma unroll
        for (int i = 0; i < 4; ++i) {
            float ev = e_lds[erow + 8 * i];
            #pragma unroll
            for (int j = 0; j < 4; ++j) {
                num_part[j]     = fmaf(rc[2*i][j],   ev, num_part[j]);
                num_part[4 + j] = fmaf(rc[2*i+1][j], ev, num_part[4 + j]);
            }
        }
    };

    #pragma unroll
    for (int k = 0; k < NSUB; k += 2) {
        body(k,     rA, rB);
        body(k + 1, rB, rA);
    }

    // ---- block-end: transpose-reduce num_part across the 8 row-groups ----
    __syncthreads();
    float* red = (float*)lds_x;   // [8][264] floats = 8448 B <= 16896 B
    {
        int g = tid >> 5, cc = (tid & 31) * 8;
        *(floatx4*)&red[g * 264 + cc]     = (floatx4){num_part[0], num_part[1], num_part[2], num_part[3]};
        *(floatx4*)&red[g * 264 + cc + 4] = (floatx4){num_part[4], num_part[5], num_part[6], num_part[7]};
    }
    __syncthreads();
    {
        float s = 0.0f;
        #pragma unroll
        for (int g = 0; g < 8; ++g) s += red[g * 264 + tid];
        ws[OFF_NP + ((size_t)bb * 16 + tblk) * 256 + tid] = s;
    }
    if (wave == 0) {
        float v = den_acc;  // lanes 0..31 partials, 32..63 zero
        v += __shfl_xor(v, 32);
        v += __shfl_xor(v, 16);
        v += __shfl_xor(v, 8);
        v += __shfl_xor(v, 4);
        v += __shfl_xor(v, 2);
        v += __shfl_xor(v, 1);
        if (lane == 0) ws[OFF_DP + bb * 16 + tblk] = v;
    }
}

// ---------------- epilogue: reduce partials, out = num / (den + eps) ----------------
__global__ void att_epilogue(const float* __restrict__ ws, float* __restrict__ out) {
    int bb = blockIdx.x;
    int d  = threadIdx.x;
    float num = 0.0f, den = 0.0f;
    #pragma unroll
    for (int k = 0; k < 16; ++k) {
        num += ws[OFF_NP + ((size_t)bb * 16 + k) * 256 + d];
        den += ws[OFF_DP + bb * 16 + k];
    }
    out[bb * D_ + d] = num / (den + EPS_);
}

extern "C" void kernel_launch(void* const* d_in, const int* in_sizes, int n_in,
                              void* d_out, int out_size, void* d_ws, size_t ws_size,
                              hipStream_t stream) {
    const float* x = (const float*)d_in[0];
    const float* W = (const float*)d_in[1];
    const float* b = (const float*)d_in[2];
    const float* u = (const float*)d_in[3];
    float* ws  = (float*)d_ws;
    float* out = (float*)d_out;

    att_prologue<<<32, 256, 0, stream>>>(W, b, u, ws);
    att_main<<<dim3(T_ / TB, B_), 256, 0, stream>>>(x, ws);
    att_epilogue<<<B_, 256, 0, stream>>>(ws, out);
}